// Round 10
// baseline (152.344 us; speedup 1.0000x reference)
//
#include <hip/hip_runtime.h>
#include <math.h>

// Problem constants
#define TT 8
#define BB 128
#define GG 256
#define DD 64
#define NCH 4     // D chunks
#define CF4 4     // float4s per cell per chunk (16 floats)

// LDS layout (round 8, verified 0-conflict): TRANSPOSED flat [q][cell] ->
// (q<<8)+cell. All access classes used here (own cell, cell+-1 row-wrapped,
// cell+-16) are consecutive-within-16-lane-groups = stride-1 ds_*_b128.
#define SIDX(q, cell) (((q) << 8) + (cell))

// ws layout: ws[pair*8 + c], c: 0 zdiff, 1 pres, 2 poolc(neg), 3 obj,
//                               4 flow_sq, 5 sum(zp), 6 sum(flow), 7 unused
// Round-2 lesson: no contended atomics in the epilogue (cost ~15 us).
//
// Round-8/9 lessons: wall == FETCH(35MB)/800GB/s in every clean round; the fix
// needs memory-level parallelism, but ANY register-borne 16xfloat4 prefetch that
// crosses a barrier blows the 128-VGPR cliff (6 failed rounds). This round uses
// global_load_lds (zero data VGPRs) for B one chunk ahead + an A-prefetch whose
// live range never crosses a barrier.

__device__ inline float wred(float v) {
#pragma unroll
    for (int off = 32; off > 0; off >>= 1) v += __shfl_xor(v, off, 64);
    return v;
}
__device__ inline float dot4(float4 a, float4 b) {
    return a.x * b.x + a.y * b.y + a.z * b.z + a.w * b.w;
}
__device__ inline float4 fabs4(float4 a) {
    return make_float4(fabsf(a.x), fabsf(a.y), fabsf(a.z), fabsf(a.w));
}
__device__ inline float4 max4(float4 a, float4 b) {
    return make_float4(fmaxf(a.x, b.x), fmaxf(a.y, b.y), fmaxf(a.z, b.z), fmaxf(a.w, b.w));
}
__device__ inline float4 scale4(float4 a, float s) {
    return make_float4(a.x * s, a.y * s, a.z * s, a.w * s);
}
__device__ inline float4 sub4(float4 a, float4 b) {
    return make_float4(a.x - b.x, a.y - b.y, a.z - b.z, a.w - b.w);
}

// Async global->LDS, 16B per lane. Dest constraint: HW writes readfirstlane(dst)
// + lane*16; our per-lane dst (q<<8)+tid coincides with that form exactly
// (lane0 of wave w -> q*4096B + w*1024B; lane l adds l*16B -> (q<<8)+tid). The
// GLOBAL source is per-lane (allowed). Tracked by vmcnt; __syncthreads drains it.
__device__ inline void glds16(const float4* gsrc, float4* lds_dst) {
    __builtin_amdgcn_global_load_lds(
        (const __attribute__((address_space(1))) unsigned int*)gsrc,
        (__attribute__((address_space(3))) unsigned int*)lds_dst,
        16, 0, 0);
}

// 3-wide clamped row max via DPP (verified rounds 1-9). old = v, bound_ctrl=false
// -> out-of-row lanes get v (identity for max): clamped semantics for free.
__device__ inline float rowmax3(float v) {
    int iv = __float_as_int(v);
    int a = __builtin_amdgcn_update_dpp(iv, iv, 0x101, 0xF, 0xF, false); // row_shl:1
    int c = __builtin_amdgcn_update_dpp(iv, iv, 0x111, 0xF, 0xF, false); // row_shr:1
    return fmaxf(v, fmaxf(__int_as_float(a), __int_as_float(c)));
}
__device__ inline float4 rowmax3_4(float4 v) {
    return make_float4(rowmax3(v.x), rowmax3(v.y), rowmax3(v.z), rowmax3(v.w));
}

// VGPR discipline: >128 costs ~20 us (6 measured casualties). Here the only
// cross-barrier tile is aA (16); pfA is issued and fully consumed (rowmax ->
// shM[nxt], rotate into aA) before the chunk's single barrier. B data never
// touches registers on the load side (global_load_lds).
__global__ __launch_bounds__(256) void pair_kernel(const float* __restrict__ zw,
                                                   const float* __restrict__ zp,
                                                   const float* __restrict__ flow,
                                                   float* __restrict__ ws) {
    const int pairIdx = blockIdx.x;            // 0 .. 7*BB-1
    const int t = pairIdx >> 7;                // BB = 128
    const int b = pairIdx & (BB - 1);
    const int tid = threadIdx.x;
    const int gi = tid >> 4, gj = tid & 15;

    __shared__ float4 shB[2][NCH * GG];        // raw B chunk, double-buffered
    __shared__ float4 shM[2][NCH * GG];        // row-max chunk, double-buffered
    __shared__ float pA[GG], pB[GG], nrmB[GG];
    __shared__ float bred[7][4];

    const float4* gA = (const float4*)zw + (size_t)(t * BB + b) * 1024;
    const float4* gB = gA + (size_t)BB * 1024;

    const float pAc = zp[(size_t)(t * BB + b) * GG + tid];
    const float pBc = zp[(size_t)((t + 1) * BB + b) * GG + tid];
    pA[tid] = pAc;                             // visible after prologue barrier
    pB[tid] = pBc;

    // 9 wrapped neighbors (jnp.roll semantics) for the object dots
    int nbc[9];
    {
        int m = 0;
#pragma unroll
        for (int di = -1; di <= 1; di++)
#pragma unroll
            for (int dj = -1; dj <= 1; dj++)
                nbc[m++] = (((gi + di) & 15) << 4) | ((gj + dj) & 15);
    }

    float zdiff = 0.f, sa = 0.f, sb = 0.f, poolDot = 0.f, poolN = 0.f;
    float dots[9] = {0.f, 0.f, 0.f, 0.f, 0.f, 0.f, 0.f, 0.f, 0.f};

    // ---- prologue: stage chunk 0 (the only exposed global latency) ----
    float4 aA[CF4];
#pragma unroll
    for (int q = 0; q < CF4; q++) glds16(&gB[tid * 16 + q], &shB[0][SIDX(q, tid)]);
#pragma unroll
    for (int q = 0; q < CF4; q++) aA[q] = gA[tid * 16 + q];
#pragma unroll
    for (int q = 0; q < CF4; q++)
        shM[0][SIDX(q, tid)] = rowmax3_4(scale4(fabs4(aA[q]), pAc));
    __syncthreads();   // drains vmcnt (glds chunk 0) + lgkm (shM stores)

    // IMPORTANT: unroll 1 -- full unroll hoists all chunks' global loads and spills.
#pragma unroll 1
    for (int c = 0; c < NCH; c++) {
        const int cur = c & 1, nxt = cur ^ 1;

        // 1. issue next-chunk staging FIRST: it flies under this chunk's compute.
        //    glds -> shB[nxt] (zero VGPRs); pfA -> regs (consumed before barrier).
        float4 pfA[CF4];
        if (c < NCH - 1) {
#pragma unroll
            for (int q = 0; q < CF4; q++)
                glds16(&gB[tid * 16 + (c + 1) * 4 + q], &shB[nxt][SIDX(q, tid)]);
#pragma unroll
            for (int q = 0; q < CF4; q++) pfA[q] = gA[tid * 16 + (c + 1) * 4 + q];
        }

        // 2. own-cell B from LDS + center stats/dot
        float4 ownB[CF4];
#pragma unroll
        for (int q = 0; q < CF4; q++) ownB[q] = shB[cur][SIDX(q, tid)];
#pragma unroll
        for (int q = 0; q < CF4; q++) {
            float4 d = sub4(ownB[q], aA[q]);
            zdiff += dot4(d, d);
            sa += dot4(aA[q], aA[q]);
            sb += dot4(ownB[q], ownB[q]);
            dots[4] += dot4(aA[q], ownB[q]);
        }
        // 3. neighbor dots: A(center, regs) . B(neighbor, shB[cur]); aA dies here
#pragma unroll
        for (int k = 0; k < 9; k++) {
            if (k == 4) continue;
#pragma unroll
            for (int q = 0; q < CF4; q++)
                dots[k] += dot4(aA[q], shB[cur][SIDX(q, nbc[k])]);
        }
        // 4. clamped col-max from shM[cur] (written last chunk), pool accumulation
        {
            float4 sm[CF4];
#pragma unroll
            for (int q = 0; q < CF4; q++) sm[q] = shM[cur][SIDX(q, tid)];
            if (gi > 0) {
#pragma unroll
                for (int q = 0; q < CF4; q++) sm[q] = max4(sm[q], shM[cur][SIDX(q, tid - 16)]);
            }
            if (gi < 15) {
#pragma unroll
                for (int q = 0; q < CF4; q++) sm[q] = max4(sm[q], shM[cur][SIDX(q, tid + 16)]);
            }
#pragma unroll
            for (int q = 0; q < CF4; q++) {
                poolDot += dot4(sm[q], fabs4(ownB[q]));
                poolN += dot4(sm[q], sm[q]);
            }
        }
        // 5. rowmax for c+1 from pfA (this consumes pfA -> implicit vmcnt wait,
        //    which also retires the older glds; by now the loads had the whole
        //    chunk compute to fly, so the wait -- and the barrier's vmcnt(0)
        //    drain -- are free). Rotate pfA -> aA. pfA never crosses the barrier.
        if (c < NCH - 1) {
#pragma unroll
            for (int q = 0; q < CF4; q++)
                shM[nxt][SIDX(q, tid)] = rowmax3_4(scale4(fabs4(pfA[q]), pAc));
#pragma unroll
            for (int q = 0; q < CF4; q++) aA[q] = pfA[q];
        }
        __syncthreads();   // ONE barrier per chunk: cur<->nxt buffers are disjoint
    }

    // ---- epilogues ----
    nrmB[tid] = sqrtf(sb);
    __syncthreads();

    // objects
    float prior_n = fmaxf(sqrtf(sa), 1e-8f);
    float sum_sim = 0.f, max_sim = -1e30f;
    bool has = false;
#pragma unroll
    for (int k = 0; k < 9; k++) {
        float nn = fmaxf(nrmB[nbc[k]], 1e-8f);
        float s = dots[k] / (prior_n * nn);
        if (pB[nbc[k]] > 0.5f) {
            sum_sim += s;
            max_sim = fmaxf(max_sim, s);
            has = true;
        }
    }
    float obj = ((pAc > 0.5f) && has) ? (sum_sim - 5.0f * max_sim) : 0.f;

    // pool
    float na_pool = fmaxf(sqrtf(poolN), 1e-6f);
    float nb_pool = fmaxf(pBc * sqrtf(sb), 1e-6f);
    float poolc = -(pBc * poolDot) / (na_pool * nb_pool) * 0.5f * (pAc + pBc);

    // flow (image t; block t=6 also handles image 7): clamped 3x3 max of zp
    float mx = pAc;
#pragma unroll
    for (int di = -1; di <= 1; di++)
#pragma unroll
        for (int dj = -1; dj <= 1; dj++) {
            if (di == 0 && dj == 0) continue;
            int ni = gi + di, nj = gj + dj;
            if (((unsigned)ni < 16u) && ((unsigned)nj < 16u))
                mx = fmaxf(mx, pA[(ni << 4) + nj]);
        }
    float f = flow[(size_t)(t * BB + b) * GG + tid];
    float fsq = 0.f;
    if (f > 0.5f) { float d = mx - f; fsq = d * d; }
    float szp = pAc, sflow = f;
    if (t == 6) {
        float mxB = pBc;
#pragma unroll
        for (int di = -1; di <= 1; di++)
#pragma unroll
            for (int dj = -1; dj <= 1; dj++) {
                if (di == 0 && dj == 0) continue;
                int ni = gi + di, nj = gj + dj;
                if (((unsigned)ni < 16u) && ((unsigned)nj < 16u))
                    mxB = fmaxf(mxB, pB[(ni << 4) + nj]);
            }
        float f7 = flow[(size_t)(7 * BB + b) * GG + tid];
        if (f7 > 0.5f) { float d = mxB - f7; fsq += d * d; }
        szp += pBc;
        sflow += f7;
    }

    // pres triple (t, t+1, t+2) for t <= 5
    float pres = 0.f;
    if (t <= 5) {
        float pC = zp[(size_t)((t + 2) * BB + b) * GG + tid];
        float s02 = pC - pAc;
        float sim = 1.f - s02 * s02;
        float d2 = pC - pBc, d0 = pAc - pBc;
        pres = sim * (d2 * d2 + d0 * d0);
    }

    // ---- block reduce 7 scalars -> private ws slot (no atomics) ----
    float r[7] = {zdiff, pres, poolc, obj, fsq, szp, sflow};
    int w = tid >> 6, lane = tid & 63;
#pragma unroll
    for (int j = 0; j < 7; j++) {
        float rv = wred(r[j]);
        if (lane == 0) bred[j][w] = rv;
    }
    __syncthreads();
    if (tid < 7)
        ws[pairIdx * 8 + tid] = bred[tid][0] + bred[tid][1] + bred[tid][2] + bred[tid][3];
}

__global__ __launch_bounds__(256) void final_kernel(const float* __restrict__ ws,
                                                    const int* __restrict__ gs,
                                                    float* __restrict__ out) {
    const int tid = threadIdx.x;
    __shared__ float bred[7][4];
    float c[7] = {0.f, 0.f, 0.f, 0.f, 0.f, 0.f, 0.f};
    for (int p = tid; p < (TT - 1) * BB; p += 256) {
        const float* r = ws + p * 8;
#pragma unroll
        for (int j = 0; j < 7; j++) c[j] += r[j];
    }
    int w = tid >> 6, lane = tid & 63;
#pragma unroll
    for (int j = 0; j < 7; j++) {
        float rv = wred(c[j]);
        if (lane == 0) bred[j][w] = rv;
    }
    __syncthreads();
    if (tid == 0) {
        float s[7];
#pragma unroll
        for (int j = 0; j < 7; j++) s[j] = bred[j][0] + bred[j][1] + bred[j][2] + bred[j][3];
        float step = (float)gs[0];
        float scale_obj = fminf(1.f, step / 200000.f);
        float scale_flow = fmaxf(0.f, 1.f - step / 100000.f);
        float flow_loss = s[4] + 100.f * fmaxf(0.f, s[5] - s[6]);
        out[0] = s[0]                       // z_what_loss * ADJ_W
               + s[1]                       // z_pres_loss * PRES_W
               + s[2]                       // pool (already negated) * POOL_W
               + s[3] * scale_obj * 10.0f   // objects * OBJ_W
               + flow_loss * scale_flow;    // FLOW_W = 1
    }
}

extern "C" void kernel_launch(void* const* d_in, const int* in_sizes, int n_in,
                              void* d_out, int out_size, void* d_ws, size_t ws_size,
                              hipStream_t stream) {
    const float* zw = (const float*)d_in[0];
    const float* zp = (const float*)d_in[1];
    const float* fl = (const float*)d_in[2];
    const int* gs = (const int*)d_in[3];
    float* ws = (float*)d_ws;

    pair_kernel<<<(TT - 1) * BB, 256, 0, stream>>>(zw, zp, fl, ws);
    final_kernel<<<1, 256, 0, stream>>>(ws, gs, (float*)d_out);
}

// Round 11
// 128.779 us; speedup vs baseline: 1.1830x; 1.1830x over previous
//
#include <hip/hip_runtime.h>
#include <math.h>

// Problem constants
#define TT 8
#define BB 128
#define GG 256
#define DD 64
#define NCH 4     // D chunks
#define CF4 4     // float4s per cell per chunk (16 floats)
#define ST 5      // padded LDS stride in float4s -- MEASURED zero-conflict (r0,r4,r7).
                  // r5 lesson: derived XOR swizzles measured 2.24M conflicts. Trust
                  // the measured layout.

// ============================ SESSION FINAL MODEL ============================
// Best kernel: this one (round 4). pair 41.8 us, total 127.8 us.
// Wall == FETCH_SIZE (35 MB) / ~850 GB/s in every clean round; this kernel is
// within ~3% of its own memory-service time. Raising the ~850 GB/s needs more
// outstanding load-bytes/CU; every HIP-level mechanism is blocked by MEASURED
// constraints on this kernel:
//  * 128-VGPR cliff costs ~24 us (6 casualties: r1 spill, r3/r5/r6/r9 136 VGPR,
//    r10 140). Any 16xfloat4 prefetch crossing a barrier blows it.
//  * global_load_lds prefetch: compiler emits s_waitcnt vmcnt(0) before every
//    s_barrier -> prefetch drained at next barrier; + addressing VGPRs (r10).
//  * Occupancy CAPACITY is not binding: 3 vs 4 blocks/CU (r8: LDS 36K, clean)
//    changed nothing; measured residency ~1.3 blocks/CU regardless.
//  * Barrier count (18->8), LDS op count (64->32/chunk), DPP dot substitution:
//    all neutral-to-negative (r4/r6/r7).
//  * Epilogue atomics cost ~15 us (r2); private ws slots + final_kernel wins.
// Remaining dur_us gap (~85 us) = harness's 2x256MB workspace fills in the
// timed window (43 us each, measured r4) -- not kernel-controllable.
// =============================================================================

// ws layout: ws[pair*8 + c], c: 0 zdiff, 1 pres, 2 poolc(neg), 3 obj,
//                               4 flow_sq, 5 sum(zp), 6 sum(flow), 7 unused

__device__ inline float wred(float v) {
#pragma unroll
    for (int off = 32; off > 0; off >>= 1) v += __shfl_xor(v, off, 64);
    return v;
}
__device__ inline float dot4(float4 a, float4 b) {
    return a.x * b.x + a.y * b.y + a.z * b.z + a.w * b.w;
}
__device__ inline float4 fabs4(float4 a) {
    return make_float4(fabsf(a.x), fabsf(a.y), fabsf(a.z), fabsf(a.w));
}
__device__ inline float4 max4(float4 a, float4 b) {
    return make_float4(fmaxf(a.x, b.x), fmaxf(a.y, b.y), fmaxf(a.z, b.z), fmaxf(a.w, b.w));
}
__device__ inline float4 scale4(float4 a, float s) {
    return make_float4(a.x * s, a.y * s, a.z * s, a.w * s);
}
__device__ inline float4 sub4(float4 a, float4 b) {
    return make_float4(a.x - b.x, a.y - b.y, a.z - b.z, a.w - b.w);
}

// 3-wide clamped row max via DPP (verified r1-r10). DPP "rows" are 16 lanes,
// matching grid rows (gj = tid & 15). old = v, bound_ctrl = false -> out-of-row
// lanes get v (identity for max): clamped semantics for free.
__device__ inline float rowmax3(float v) {
    int iv = __float_as_int(v);
    int a = __builtin_amdgcn_update_dpp(iv, iv, 0x101, 0xF, 0xF, false); // row_shl:1
    int c = __builtin_amdgcn_update_dpp(iv, iv, 0x111, 0xF, 0xF, false); // row_shr:1
    return fmaxf(v, fmaxf(__int_as_float(a), __int_as_float(c)));
}
__device__ inline float4 rowmax3_4(float4 v) {
    return make_float4(rowmax3(v.x), rowmax3(v.y), rowmax3(v.z), rowmax3(v.w));
}

// VGPR discipline: plain __launch_bounds__(256) (a min-waves arg drove the target
// to 64 VGPR -> 326 MB spill, r1). No prefetch of any kind (see model above).
// This structure measures 120 VGPR, 0 spill.
__global__ __launch_bounds__(256) void pair_kernel(const float* __restrict__ zw,
                                                   const float* __restrict__ zp,
                                                   const float* __restrict__ flow,
                                                   float* __restrict__ ws) {
    const int pairIdx = blockIdx.x;            // 0 .. 7*BB-1
    const int t = pairIdx >> 7;                // BB = 128
    const int b = pairIdx & (BB - 1);
    const int tid = threadIdx.x;
    const int gi = tid >> 4, gj = tid & 15;

    __shared__ float4 shB[GG * ST];            // raw B chunk (neighbor dots)
    __shared__ float4 shM[GG * ST];            // row-max chunk (col-max pass)
    __shared__ float pA[GG], pB[GG], nrmB[GG];
    __shared__ float bred[7][4];

    const float4* gA = (const float4*)zw + (size_t)(t * BB + b) * 1024;
    const float4* gB = gA + (size_t)BB * 1024;

    const float pAc = zp[(size_t)(t * BB + b) * GG + tid];
    const float pBc = zp[(size_t)((t + 1) * BB + b) * GG + tid];
    pA[tid] = pAc;                             // visibility covered by chunk-loop syncs
    pB[tid] = pBc;

    // 9 wrapped neighbors (jnp.roll semantics) + in-bounds bitmask (clamped ops)
    int nbc[9];
    unsigned inbM = 0;
    {
        int m = 0;
#pragma unroll
        for (int di = -1; di <= 1; di++) {
#pragma unroll
            for (int dj = -1; dj <= 1; dj++) {
                nbc[m] = (((gi + di) & 15) << 4) | ((gj + dj) & 15);
                if (((unsigned)(gi + di) < 16u) && ((unsigned)(gj + dj) < 16u))
                    inbM |= (1u << m);
                m++;
            }
        }
    }

    float zdiff = 0.f, sa = 0.f, sb = 0.f, poolDot = 0.f, poolN = 0.f;
    float dots[9] = {0.f, 0.f, 0.f, 0.f, 0.f, 0.f, 0.f, 0.f, 0.f};
    const int sbase = tid * ST;

    // IMPORTANT: unroll 1 -- full unroll hoists all chunks' global loads and spills.
#pragma unroll 1
    for (int c = 0; c < NCH; c++) {
        float4 aA[CF4], aB[CF4];
#pragma unroll
        for (int q = 0; q < CF4; q++) {
            aA[q] = gA[tid * 16 + c * 4 + q];
            aB[q] = gB[tid * 16 + c * 4 + q];
        }

        // stage raw B and DPP row-max into separate buffers -> one sync serves both
#pragma unroll
        for (int q = 0; q < CF4; q++) {
            shB[sbase + q] = aB[q];
            shM[sbase + q] = rowmax3_4(scale4(fabs4(aA[q]), pAc));
        }
        // register-local stats + center dot (no LDS dependence; keeps waves busy
        // while others reach the barrier)
#pragma unroll
        for (int q = 0; q < CF4; q++) {
            float4 d = sub4(aB[q], aA[q]);
            zdiff += dot4(d, d);
            sa += dot4(aA[q], aA[q]);
            sb += dot4(aB[q], aB[q]);
            dots[4] += dot4(aA[q], aB[q]);
        }
        __syncthreads();

        // neighbor dots: A(center, regs) . B(neighbor, shB)
#pragma unroll
        for (int k = 0; k < 9; k++) {
            if (k == 4) continue;
            int base = nbc[k] * ST;
#pragma unroll
            for (int q = 0; q < CF4; q++) dots[k] += dot4(aA[q], shB[base + q]);
        }
        // clamped col-max of row-max, then pool accumulation
        {
            float4 sm[CF4];
#pragma unroll
            for (int q = 0; q < CF4; q++) sm[q] = shM[sbase + q];
            if (gi > 0) {
#pragma unroll
                for (int q = 0; q < CF4; q++) sm[q] = max4(sm[q], shM[sbase - 16 * ST + q]);
            }
            if (gi < 15) {
#pragma unroll
                for (int q = 0; q < CF4; q++) sm[q] = max4(sm[q], shM[sbase + 16 * ST + q]);
            }
#pragma unroll
            for (int q = 0; q < CF4; q++) {
                poolDot += dot4(sm[q], fabs4(aB[q]));
                poolN += dot4(sm[q], sm[q]);
            }
        }
        __syncthreads();   // all reads of shB/shM done before next chunk's stores
    }

    // ---- epilogues ----
    nrmB[tid] = sqrtf(sb);
    __syncthreads();

    // objects
    float prior_n = fmaxf(sqrtf(sa), 1e-8f);
    float sum_sim = 0.f, max_sim = -1e30f;
    bool has = false;
#pragma unroll
    for (int k = 0; k < 9; k++) {
        float nn = fmaxf(nrmB[nbc[k]], 1e-8f);
        float s = dots[k] / (prior_n * nn);
        if (pB[nbc[k]] > 0.5f) {
            sum_sim += s;
            max_sim = fmaxf(max_sim, s);
            has = true;
        }
    }
    float obj = ((pAc > 0.5f) && has) ? (sum_sim - 5.0f * max_sim) : 0.f;

    // pool
    float na_pool = fmaxf(sqrtf(poolN), 1e-6f);
    float nb_pool = fmaxf(pBc * sqrtf(sb), 1e-6f);
    float poolc = -(pBc * poolDot) / (na_pool * nb_pool) * 0.5f * (pAc + pBc);

    // flow (image t; block t=6 also handles image 7): clamped 3x3 max of zp
    float mx = pAc;
#pragma unroll
    for (int k = 0; k < 9; k++)
        if (k != 4 && ((inbM >> k) & 1u)) mx = fmaxf(mx, pA[nbc[k]]);
    float f = flow[(size_t)(t * BB + b) * GG + tid];
    float fsq = 0.f;
    if (f > 0.5f) { float d = mx - f; fsq = d * d; }
    float szp = pAc, sflow = f;
    if (t == 6) {
        float mxB = pBc;
#pragma unroll
        for (int k = 0; k < 9; k++)
            if (k != 4 && ((inbM >> k) & 1u)) mxB = fmaxf(mxB, pB[nbc[k]]);
        float f7 = flow[(size_t)(7 * BB + b) * GG + tid];
        if (f7 > 0.5f) { float d = mxB - f7; fsq += d * d; }
        szp += pBc;
        sflow += f7;
    }

    // pres triple (t, t+1, t+2) for t <= 5
    float pres = 0.f;
    if (t <= 5) {
        float pC = zp[(size_t)((t + 2) * BB + b) * GG + tid];
        float s02 = pC - pAc;
        float sim = 1.f - s02 * s02;
        float d2 = pC - pBc, d0 = pAc - pBc;
        pres = sim * (d2 * d2 + d0 * d0);
    }

    // ---- block reduce 7 scalars -> private ws slot (no atomics) ----
    float r[7] = {zdiff, pres, poolc, obj, fsq, szp, sflow};
    int w = tid >> 6, lane = tid & 63;
#pragma unroll
    for (int j = 0; j < 7; j++) {
        float rv = wred(r[j]);
        if (lane == 0) bred[j][w] = rv;
    }
    __syncthreads();
    if (tid < 7)
        ws[pairIdx * 8 + tid] = bred[tid][0] + bred[tid][1] + bred[tid][2] + bred[tid][3];
}

__global__ __launch_bounds__(256) void final_kernel(const float* __restrict__ ws,
                                                    const int* __restrict__ gs,
                                                    float* __restrict__ out) {
    const int tid = threadIdx.x;
    __shared__ float bred[7][4];
    float c[7] = {0.f, 0.f, 0.f, 0.f, 0.f, 0.f, 0.f};
    for (int p = tid; p < (TT - 1) * BB; p += 256) {
        const float* r = ws + p * 8;
#pragma unroll
        for (int j = 0; j < 7; j++) c[j] += r[j];
    }
    int w = tid >> 6, lane = tid & 63;
#pragma unroll
    for (int j = 0; j < 7; j++) {
        float rv = wred(c[j]);
        if (lane == 0) bred[j][w] = rv;
    }
    __syncthreads();
    if (tid == 0) {
        float s[7];
#pragma unroll
        for (int j = 0; j < 7; j++) s[j] = bred[j][0] + bred[j][1] + bred[j][2] + bred[j][3];
        float step = (float)gs[0];
        float scale_obj = fminf(1.f, step / 200000.f);
        float scale_flow = fmaxf(0.f, 1.f - step / 100000.f);
        float flow_loss = s[4] + 100.f * fmaxf(0.f, s[5] - s[6]);
        out[0] = s[0]                       // z_what_loss * ADJ_W
               + s[1]                       // z_pres_loss * PRES_W
               + s[2]                       // pool (already negated) * POOL_W
               + s[3] * scale_obj * 10.0f   // objects * OBJ_W
               + flow_loss * scale_flow;    // FLOW_W = 1
    }
}

extern "C" void kernel_launch(void* const* d_in, const int* in_sizes, int n_in,
                              void* d_out, int out_size, void* d_ws, size_t ws_size,
                              hipStream_t stream) {
    const float* zw = (const float*)d_in[0];
    const float* zp = (const float*)d_in[1];
    const float* fl = (const float*)d_in[2];
    const int* gs = (const int*)d_in[3];
    float* ws = (float*)d_ws;

    pair_kernel<<<(TT - 1) * BB, 256, 0, stream>>>(zw, zp, fl, ws);
    final_kernel<<<1, 256, 0, stream>>>(ws, gs, (float*)d_out);
}